// Round 1
// 12903.677 us; speedup vs baseline: 1.0969x; 1.0969x over previous
//
#include <hip/hip_runtime.h>
#include <math.h>

static constexpr int NB  = 1024;
static constexpr int NS  = 100;
static constexpr int NH  = 128;
static constexpr int GPB = 2;           // batches per block (1 weight read -> 2 batches)
static constexpr int NTHR = 256;
static constexpr int NBLK = NB / GPB;   // 512 blocks = 2 per CU (overlap barrier stalls)

static constexpr int OUT_MU = 0;
static constexpr int OUT_LV = NB * NS;
static constexpr int OUT_Z  = 2 * NB * NS;
static constexpr int OUT_TI = 3 * NB * NS;
static constexpr int OUT_LP = 4 * NB * NS;

#define NEGF (-3.4e38f)

// f32 dot of one f32 weight row against TWO f32 LDS vectors (row loaded once).
// Per-accumulator fmaf chain identical to R9's dot2f (k ascending).
template<int C4>
__device__ __forceinline__ void dot2f(const float* __restrict__ w,
        const float* __restrict__ x0, const float* __restrict__ x1, float& r0, float& r1)
{
    const float4* W = reinterpret_cast<const float4*>(w);
    float a0 = 0.f, a1 = 0.f;
    #pragma unroll 8
    for (int c = 0; c < C4; ++c) {
        float4 u = W[c];
        int k = 4 * c;
        a0 = fmaf(u.x, x0[k], a0); a0 = fmaf(u.y, x0[k+1], a0); a0 = fmaf(u.z, x0[k+2], a0); a0 = fmaf(u.w, x0[k+3], a0);
        a1 = fmaf(u.x, x1[k], a1); a1 = fmaf(u.y, x1[k+1], a1); a1 = fmaf(u.z, x1[k+2], a1); a1 = fmaf(u.w, x1[k+3], a1);
    }
    r0 = a0; r1 = a1;
}

// Single-vector variant, same per-accumulator chain (k ascending).
template<int C4>
__device__ __forceinline__ void dot1f(const float* __restrict__ w,
        const float* __restrict__ x0, float& r0)
{
    const float4* W = reinterpret_cast<const float4*>(w);
    float a0 = 0.f;
    #pragma unroll 8
    for (int c = 0; c < C4; ++c) {
        float4 u = W[c];
        int k = 4 * c;
        a0 = fmaf(u.x, x0[k], a0); a0 = fmaf(u.y, x0[k+1], a0); a0 = fmaf(u.z, x0[k+2], a0); a0 = fmaf(u.w, x0[k+3], a0);
    }
    r0 = a0;
}

// f64-accum dot of an f32 row vs f32 LDS vector (mu/lv epilogue) — R9 verbatim.
template<int C4>
__device__ __forceinline__ double dotwd(const float* __restrict__ w, const float* __restrict__ x)
{
    const float4* W = reinterpret_cast<const float4*>(w);
    double a = 0.0;
    #pragma unroll 8
    for (int c = 0; c < C4; ++c) {
        float4 u = W[c];
        const float* p = x + 4 * c;
        a = fma((double)u.x, (double)p[0], a);
        a = fma((double)u.y, (double)p[1], a);
        a = fma((double)u.z, (double)p[2], a);
        a = fma((double)u.w, (double)p[3], a);
    }
    return a;
}

// GRU nonlinearity (f64 internals, f32 storage) — R9 verbatim.
__device__ __forceinline__ void gruc(const float* __restrict__ bih, const float* __restrict__ bhh,
        const float* __restrict__ pa, const float* __restrict__ pb, float* __restrict__ h, int j)
{
    double r = 1.0 / (1.0 + exp(-(((double)pa[j]        + (double)bih[j])        + ((double)pb[j]        + (double)bhh[j]))));
    double z = 1.0 / (1.0 + exp(-(((double)pa[NH + j]   + (double)bih[NH + j])   + ((double)pb[NH + j]   + (double)bhh[NH + j]))));
    double n = tanh(((double)pa[2*NH + j] + (double)bih[2*NH + j]) + r * ((double)pb[2*NH + j] + (double)bhh[2*NH + j]));
    h[j] = (float)((1.0 - z) * n + z * (double)h[j]);
}

__global__ __launch_bounds__(NTHR) void vae_v12(
    const float* __restrict__ instance, const int* __restrict__ sol1,
    const int* __restrict__ sol2, const float* __restrict__ eps,
    const float* __restrict__ emb_i_W, const float* __restrict__ emb_i_b,
    const float* __restrict__ emb_r_W, const float* __restrict__ emb_r_b,
    const float* __restrict__ attn_W, const float* __restrict__ attn_v,
    const float* __restrict__ gru_Wih, const float* __restrict__ gru_Whh,
    const float* __restrict__ gru_bih, const float* __restrict__ gru_bhh,
    const float* __restrict__ grud_Wih, const float* __restrict__ grud_Whh,
    const float* __restrict__ grud_bih, const float* __restrict__ grud_bhh,
    const float* __restrict__ efc1_W, const float* __restrict__ efc1_b,
    const float* __restrict__ efc2_W, const float* __restrict__ efc2_b,
    const float* __restrict__ ptr_W, const float* __restrict__ ptr_v,
    const float* __restrict__ pfc1_W, const float* __restrict__ pfc1_b,
    const float* __restrict__ pfc2_W, const float* __restrict__ pfc2_b,
    float* __restrict__ out)
{
    __shared__ float  s_x[GPB][360];            // enc: [ref|ctx]; dec: [ctx|Z|ref]
    __shared__ float  s_h1[GPB][NH], s_h2[GPB][NH], s_fco[GPB][NH];
    __shared__ float  s_fch[GPB][256];
    __shared__ float  s_pa[GPB][3 * NH], s_pb[GPB][3 * NH];
    __shared__ double s_qh[GPB][NH];            // Ab + rnn-side q (f64, R9 semantics)
    __shared__ double dA0a[NH], dA1a[NH], dAba[NH];   // attn collapse (f64)
    __shared__ double dA0p[NH], dA1p[NH], dAbp[NH];   // ptr collapse (f64)
    __shared__ float  s_lg[GPB][NS], s_a[GPB][NS];
    __shared__ float  s_c0[GPB][NS], s_c1[GPB][NS], s_msk[GPB][NS];
    __shared__ float  t_wi0[NH], t_wi1[NH], t_bi[NH];
    __shared__ float  t_wr0[NH], t_wr1[NH], t_br[NH];
    __shared__ float  t_va[NH], t_vp[NH];
    __shared__ float  s_red[GPB][16];           // f32 max partials
    __shared__ double s_redd[GPB][16];          // f64 sum partials
    __shared__ int    s_ri[GPB][16];
    __shared__ float  s_mx[GPB];
    __shared__ double s_se[GPB];
    __shared__ float  s_rc0[GPB], s_rc1[GPB];

    const int tid = threadIdx.x;
    const int bbase = blockIdx.x * GPB;
    const int j = tid & (NH - 1);
    const int half = tid >> 7;
    const int g = half;                 // this thread's batch group for elementwise phases

    // ---------- init ----------
    if (tid < NH) {
        t_wi0[tid] = emb_i_W[2*tid]; t_wi1[tid] = emb_i_W[2*tid+1]; t_bi[tid] = emb_i_b[tid];
        t_wr0[tid] = emb_r_W[2*tid]; t_wr1[tid] = emb_r_W[2*tid+1]; t_br[tid] = emb_r_b[tid];
        t_va[tid] = attn_v[tid]; t_vp[tid] = ptr_v[tid];
    }
    for (int i = tid; i < GPB * NS; i += NTHR) {
        int gg = i / NS, s = i - gg * NS;
        s_c0[gg][s] = instance[(size_t)((bbase + gg) * NS + s) * 2 + 0];
        s_c1[gg][s] = instance[(size_t)((bbase + gg) * NS + s) * 2 + 1];
    }
    s_h1[g][j] = 0.f;
    s_h2[g][j] = 0.f;
    __syncthreads();
    {   // collapse tables: f64 exact algebra (R9 verbatim)
        const float* Wm = (half == 0) ? attn_W : ptr_W;
        double a0 = 0.0, a1 = 0.0, ab = 0.0;
        for (int k = 0; k < NH; ++k) {
            double wv = (double)Wm[(size_t)k * NH + j];
            a0 = fma((double)t_wi0[k], wv, a0);
            a1 = fma((double)t_wi1[k], wv, a1);
            ab = fma((double)t_bi[k],  wv, ab);
        }
        if (half == 0) { dA0a[j] = a0; dA1a[j] = a1; dAba[j] = ab; }
        else           { dA0p[j] = a0; dA1p[j] = a1; dAbp[j] = ab; }
    }
    {   // initial encoder ref_h
        int sp = sol1[(bbase + g) * NS + 0];
        s_x[g][j] = fmaf(s_c0[g][sp], t_wr0[j], fmaf(s_c1[g][sp], t_wr1[j], t_br[j]));
    }
    __syncthreads();

    // ---------- encoder ----------
    for (int t = 1; t < NS; ++t) {
        if (half == 0) {    // GRU1 x-side: one row read -> 2 batches
            float r0, r1;
            dot2f<32>(gru_Wih + (size_t)j          * NH, s_x[0], s_x[1], r0, r1);
            s_pa[0][j] = r0; s_pa[1][j] = r1;
            dot2f<32>(gru_Wih + (size_t)(NH + j)   * NH, s_x[0], s_x[1], r0, r1);
            s_pa[0][NH + j] = r0; s_pa[1][NH + j] = r1;
            dot2f<32>(gru_Wih + (size_t)(2*NH + j) * NH, s_x[0], s_x[1], r0, r1);
            s_pa[0][2*NH + j] = r0; s_pa[1][2*NH + j] = r1;
        } else {            // GRU1 h-side
            float r0, r1;
            dot2f<32>(gru_Whh + (size_t)j          * NH, s_h1[0], s_h1[1], r0, r1);
            s_pb[0][j] = r0; s_pb[1][j] = r1;
            dot2f<32>(gru_Whh + (size_t)(NH + j)   * NH, s_h1[0], s_h1[1], r0, r1);
            s_pb[0][NH + j] = r0; s_pb[1][NH + j] = r1;
            dot2f<32>(gru_Whh + (size_t)(2*NH + j) * NH, s_h1[0], s_h1[1], r0, r1);
            s_pb[0][2*NH + j] = r0; s_pb[1][2*NH + j] = r1;
        }
        __syncthreads();
        gruc(gru_bih, gru_bhh, s_pa[g], s_pb[g], s_h1[g], j);
        __syncthreads();
        {   // q = Ab + h1 . attn_W[128:256] columns (f64 accum, R9 verbatim)
            const float* col = attn_W + (size_t)NH * NH + j;
            double a0 = 0.0;
            for (int k = 0; k < NH; ++k) {
                double wv = (double)col[(size_t)k * NH];
                a0 = fma(wv, (double)s_h1[g][k], a0);
            }
            s_qh[g][j] = dAba[j] + a0;
        }
        __syncthreads();
        if (j < NS) {   // relu head logits (f64 pre/accum, R9 verbatim)
            double c00 = (double)s_c0[g][j], c10 = (double)s_c1[g][j];
            double acc0 = 0.0;
            for (int h = 0; h < NH; ++h) {
                double A0 = dA0a[h], A1 = dA1a[h], v = (double)t_va[h];
                double p0 = fma(c00, A0, fma(c10, A1, s_qh[g][h]));
                acc0 = fma(fmax(p0, 0.0), v, acc0);
            }
            s_lg[g][j] = (float)acc0;
        }
        __syncthreads();
        if (j < 16) {   // segmented max (exact, order-free)
            float m0 = NEGF;
            for (int s = j; s < NS; s += 16) m0 = fmaxf(m0, s_lg[g][s]);
            s_red[g][j] = m0;
        }
        __syncthreads();
        if (tid < GPB) {
            float m = NEGF;
            for (int i = 0; i < 16; ++i) m = fmaxf(m, s_red[tid][i]);
            s_mx[tid] = m;
        }
        __syncthreads();
        if (j < NS) {   // exps: f64 exp narrowed to f32 (R9 semantics)
            s_a[g][j] = (float)exp((double)s_lg[g][j] - (double)s_mx[g]);
        }
        __syncthreads();
        if (j < 16) {   // segmented f64 sum
            double t0 = 0.0;
            for (int s = j; s < NS; s += 16) t0 += (double)s_a[g][s];
            s_redd[g][j] = t0;
        }
        __syncthreads();
        if (tid < GPB) {
            double se = 0.0;
            for (int i = 0; i < 16; ++i) se += s_redd[tid][i];
            s_se[tid] = se;
        }
        __syncthreads();
        if (j < NS) {   // normalize first (R9 semantics)
            s_a[g][j] = (float)((double)s_a[g][j] / s_se[g]);
        }
        __syncthreads();
        {   // context (f64 accum of f32 probs x f32 ih, R9 verbatim) + new ref_h
            float w0 = t_wi0[j], w1 = t_wi1[j], bb = t_bi[j];
            double a0 = 0.0;
            for (int s = 0; s < NS; ++s) {
                float ih0 = fmaf(s_c0[g][s], w0, fmaf(s_c1[g][s], w1, bb));
                a0 += (double)s_a[g][s] * (double)ih0;
            }
            s_x[g][NH + j] = (float)a0;
            int sp = sol1[(bbase + g) * NS + t];
            s_x[g][j] = fmaf(s_c0[g][sp], t_wr0[j], fmaf(s_c1[g][sp], t_wr1[j], t_br[j]));
        }
        __syncthreads();
        if (half == 0) {    // GRUd x-side (K=256)
            float r0, r1;
            dot2f<64>(grud_Wih + (size_t)j          * 256, s_x[0], s_x[1], r0, r1);
            s_pa[0][j] = r0; s_pa[1][j] = r1;
            dot2f<64>(grud_Wih + (size_t)(NH + j)   * 256, s_x[0], s_x[1], r0, r1);
            s_pa[0][NH + j] = r0; s_pa[1][NH + j] = r1;
            dot2f<64>(grud_Wih + (size_t)(2*NH + j) * 256, s_x[0], s_x[1], r0, r1);
            s_pa[0][2*NH + j] = r0; s_pa[1][2*NH + j] = r1;
        } else {            // GRUd h-side
            float r0, r1;
            dot2f<32>(grud_Whh + (size_t)j          * NH, s_h2[0], s_h2[1], r0, r1);
            s_pb[0][j] = r0; s_pb[1][j] = r1;
            dot2f<32>(grud_Whh + (size_t)(NH + j)   * NH, s_h2[0], s_h2[1], r0, r1);
            s_pb[0][NH + j] = r0; s_pb[1][NH + j] = r1;
            dot2f<32>(grud_Whh + (size_t)(2*NH + j) * NH, s_h2[0], s_h2[1], r0, r1);
            s_pb[0][2*NH + j] = r0; s_pb[1][2*NH + j] = r1;
        }
        __syncthreads();
        gruc(grud_bih, grud_bhh, s_pa[g], s_pb[g], s_h2[g], j);
        __syncthreads();
    }

    // ---------- epilogue: mu, lv, Z (f64, R9 verbatim) ----------
    for (int idx = tid; idx < GPB * NS; idx += NTHR) {
        int gg = idx / NS, s = idx - gg * NS, b = bbase + gg;
        double mu = dotwd<32>(efc1_W + (size_t)s * NH, s_h2[gg]) + (double)efc1_b[s];
        double lv = dotwd<32>(efc2_W + (size_t)s * NH, s_h2[gg]) + (double)efc2_b[s];
        double z  = mu + (double)eps[(size_t)b * NS + s] * exp(0.5 * lv);
        out[OUT_MU + b * NS + s] = (float)mu;
        out[OUT_LV + b * NS + s] = (float)lv;
        out[OUT_Z  + b * NS + s] = (float)z;
        s_x[gg][NH + s] = (float)z;   // decoder Z slot [128..227]
    }
    for (int i = tid; i < GPB * NS; i += NTHR) {
        int gg = i / NS, s = i - gg * NS;
        s_msk[gg][s] = 1.f;
    }
    s_h1[g][j] = 0.f;
    __syncthreads();
    if (tid < GPB) {
        int b = bbase + tid;
        int s0 = sol2[b * NS + 0];
        s_msk[tid][s0] = 0.f;
        s_rc0[tid] = s_c0[tid][s0];
        s_rc1[tid] = s_c1[tid][s0];
        out[OUT_TI + b * NS + 0] = (float)s0;
    }
    __syncthreads();

    // ---------- decoder ----------
    for (int t = 1; t < NS; ++t) {
        s_x[g][228 + j] = fmaf(s_rc0[g], t_wr0[j], fmaf(s_rc1[g], t_wr1[j], t_br[j]));
        __syncthreads();
        if (half == 0) {    // GRU1 x-side on ref
            float r0, r1;
            dot2f<32>(gru_Wih + (size_t)j          * NH, s_x[0]+228, s_x[1]+228, r0, r1);
            s_pa[0][j] = r0; s_pa[1][j] = r1;
            dot2f<32>(gru_Wih + (size_t)(NH + j)   * NH, s_x[0]+228, s_x[1]+228, r0, r1);
            s_pa[0][NH + j] = r0; s_pa[1][NH + j] = r1;
            dot2f<32>(gru_Wih + (size_t)(2*NH + j) * NH, s_x[0]+228, s_x[1]+228, r0, r1);
            s_pa[0][2*NH + j] = r0; s_pa[1][2*NH + j] = r1;
        } else {
            float r0, r1;
            dot2f<32>(gru_Whh + (size_t)j          * NH, s_h1[0], s_h1[1], r0, r1);
            s_pb[0][j] = r0; s_pb[1][j] = r1;
            dot2f<32>(gru_Whh + (size_t)(NH + j)   * NH, s_h1[0], s_h1[1], r0, r1);
            s_pb[0][NH + j] = r0; s_pb[1][NH + j] = r1;
            dot2f<32>(gru_Whh + (size_t)(2*NH + j) * NH, s_h1[0], s_h1[1], r0, r1);
            s_pb[0][2*NH + j] = r0; s_pb[1][2*NH + j] = r1;
        }
        __syncthreads();
        gruc(gru_bih, gru_bhh, s_pa[g], s_pb[g], s_h1[g], j);
        __syncthreads();
        {   // q (attn, f64)
            const float* col = attn_W + (size_t)NH * NH + j;
            double a0 = 0.0;
            for (int k = 0; k < NH; ++k) {
                double wv = (double)col[(size_t)k * NH];
                a0 = fma(wv, (double)s_h1[g][k], a0);
            }
            s_qh[g][j] = dAba[j] + a0;
        }
        __syncthreads();
        if (j < NS) {   // relu head (f64)
            double c00 = (double)s_c0[g][j], c10 = (double)s_c1[g][j];
            double acc0 = 0.0;
            for (int h = 0; h < NH; ++h) {
                double A0 = dA0a[h], A1 = dA1a[h], v = (double)t_va[h];
                double p0 = fma(c00, A0, fma(c10, A1, s_qh[g][h]));
                acc0 = fma(fmax(p0, 0.0), v, acc0);
            }
            s_lg[g][j] = (float)acc0;
        }
        __syncthreads();
        if (j < 16) {
            float m0 = NEGF;
            for (int s = j; s < NS; s += 16) m0 = fmaxf(m0, s_lg[g][s]);
            s_red[g][j] = m0;
        }
        __syncthreads();
        if (tid < GPB) {
            float m = NEGF;
            for (int i = 0; i < 16; ++i) m = fmaxf(m, s_red[tid][i]);
            s_mx[tid] = m;
        }
        __syncthreads();
        if (j < NS) {
            s_a[g][j] = (float)exp((double)s_lg[g][j] - (double)s_mx[g]);
        }
        __syncthreads();
        if (j < 16) {
            double t0 = 0.0;
            for (int s = j; s < NS; s += 16) t0 += (double)s_a[g][s];
            s_redd[g][j] = t0;
        }
        __syncthreads();
        if (tid < GPB) {
            double se = 0.0;
            for (int i = 0; i < 16; ++i) se += s_redd[tid][i];
            s_se[tid] = se;
        }
        __syncthreads();
        if (j < NS) {
            s_a[g][j] = (float)((double)s_a[g][j] / s_se[g]);
        }
        __syncthreads();
        {   // context -> s_x[g][0..127]
            float w0 = t_wi0[j], w1 = t_wi1[j], bb = t_bi[j];
            double a0 = 0.0;
            for (int s = 0; s < NS; ++s) {
                float ih0 = fmaf(s_c0[g][s], w0, fmaf(s_c1[g][s], w1, bb));
                a0 += (double)s_a[g][s] * (double)ih0;
            }
            s_x[g][j] = (float)a0;
        }
        __syncthreads();
        {   // pfc1: row i = tid, one read -> 2 batches (f32, R9 chain)
            float r0, r1;
            dot2f<89>(pfc1_W + (size_t)tid * 356, s_x[0], s_x[1], r0, r1);
            float bb = pfc1_b[tid];
            s_fch[0][tid] = r0 + bb; s_fch[1][tid] = r1 + bb;
        }
        __syncthreads();
        {   // pfc2 (f32)
            float r0;
            dot1f<64>(pfc2_W + (size_t)j * 256, s_fch[g], r0);
            s_fco[g][j] = r0 + pfc2_b[j];
        }
        __syncthreads();
        {   // q2 (ptr, f64)
            const float* col = ptr_W + (size_t)NH * NH + j;
            double a0 = 0.0;
            for (int k = 0; k < NH; ++k) {
                double wv = (double)col[(size_t)k * NH];
                a0 = fma(wv, (double)s_fco[g][k], a0);
            }
            s_qh[g][j] = dAbp[j] + a0;
        }
        __syncthreads();
        if (j < NS) {   // tanh pointer head (f64 pre, tanhf, R9 verbatim)
            double c00 = (double)s_c0[g][j], c10 = (double)s_c1[g][j];
            double acc0 = 0.0;
            for (int h = 0; h < NH; ++h) {
                double A0 = dA0p[h], A1 = dA1p[h], v = (double)t_vp[h];
                double p0 = fma(c00, A0, fma(c10, A1, s_qh[g][h]));
                acc0 = fma((double)tanhf((float)p0), v, acc0);
            }
            s_lg[g][j] = (float)acc0;
        }
        __syncthreads();
        if (j < 16) {   // masked segmented max of logits (for exp stability only)
            float m0 = NEGF;
            for (int s = j; s < NS; s += 16) {
                float v0 = (s_msk[g][s] > 0.f) ? s_lg[g][s] : NEGF;
                m0 = fmaxf(m0, v0);
            }
            s_red[g][j] = m0;
        }
        __syncthreads();
        if (tid < GPB) {
            float m = NEGF;
            for (int i = 0; i < 16; ++i) m = fmaxf(m, s_red[tid][i]);
            s_mx[tid] = m;
        }
        __syncthreads();
        if (j < NS) {   // masked exps, f64 exp narrowed to f32 (R9 semantics)
            s_a[g][j] = (s_msk[g][j] > 0.f) ? (float)exp((double)s_lg[g][j] - (double)s_mx[g]) : 0.f;
        }
        __syncthreads();
        if (j < 16) {   // argmax over f32 EXPS (prob-equivalent), first-occurrence ties
            float m0 = -1.f; int i0 = 0;
            double t0 = 0.0;
            for (int s = j; s < NS; s += 16) {
                float a0v = s_a[g][s];
                t0 += (double)a0v;
                if (a0v > m0) { m0 = a0v; i0 = s; }
            }
            s_red[g][j] = m0; s_ri[g][j] = i0; s_redd[g][j] = t0;
        }
        __syncthreads();
        if (tid < GPB) {   // fold: first-occurrence argmax + se; outputs + carry
            int gg = tid, b = bbase + gg;
            float m = -1.f; int mi = NS; double se = 0.0;
            for (int i = 0; i < 16; ++i) {
                se += s_redd[gg][i];
                float v = s_red[gg][i]; int vi = s_ri[gg][i];
                if (v > m || (v == m && vi < mi)) { m = v; mi = vi; }
            }
            int pt = sol2[b * NS + t];
            double logp = log((double)s_a[gg][pt] / se);
            out[OUT_TI + b * NS + t]             = (float)mi;
            out[OUT_LP + b * (NS - 1) + (t - 1)] = (float)logp;
            s_msk[gg][pt] = 0.f;
            s_rc0[gg] = s_c0[gg][pt];
            s_rc1[gg] = s_c1[gg][pt];
        }
        __syncthreads();
    }
}

extern "C" void kernel_launch(void* const* d_in, const int* in_sizes, int n_in,
                              void* d_out, int out_size, void* d_ws, size_t ws_size,
                              hipStream_t stream)
{
    (void)in_sizes; (void)n_in; (void)out_size; (void)d_ws; (void)ws_size;
    vae_v12<<<NBLK, NTHR, 0, stream>>>(
        (const float*)d_in[0], (const int*)d_in[1], (const int*)d_in[2], (const float*)d_in[3],
        (const float*)d_in[4], (const float*)d_in[5], (const float*)d_in[6], (const float*)d_in[7],
        (const float*)d_in[8], (const float*)d_in[9], (const float*)d_in[10], (const float*)d_in[11],
        (const float*)d_in[12], (const float*)d_in[13], (const float*)d_in[14], (const float*)d_in[15],
        (const float*)d_in[16], (const float*)d_in[17], (const float*)d_in[18], (const float*)d_in[19],
        (const float*)d_in[20], (const float*)d_in[21], (const float*)d_in[22], (const float*)d_in[23],
        (const float*)d_in[24], (const float*)d_in[25], (const float*)d_in[26], (const float*)d_in[27],
        (float*)d_out);
}

// Round 2
// 12718.074 us; speedup vs baseline: 1.1129x; 1.0146x over previous
//
#include <hip/hip_runtime.h>
#include <math.h>

static constexpr int NB  = 1024;
static constexpr int NS  = 100;
static constexpr int NH  = 128;
static constexpr int GPB = 2;           // batches per block (1 weight read -> 2 batches)
static constexpr int NTHR = 256;
static constexpr int NBLK = NB / GPB;   // 512 blocks = 2 per CU

static constexpr int OUT_MU = 0;
static constexpr int OUT_LV = NB * NS;
static constexpr int OUT_Z  = 2 * NB * NS;
static constexpr int OUT_TI = 3 * NB * NS;
static constexpr int OUT_LP = 4 * NB * NS;

#define NEGF (-3.4e38f)

// Fused 3-row x 2-batch f32 dot: x vectors read from LDS ONCE per chunk (float4),
// applied to 3 weight rows. Per-accumulator fmaf chain is k-ascending — bitwise
// identical to the previous dot2f per-row chains.
template<int C4>
__device__ __forceinline__ void dot2x3f(const float* __restrict__ wr0,
        const float* __restrict__ wr1, const float* __restrict__ wr2,
        const float* __restrict__ x0, const float* __restrict__ x1,
        float& r00, float& r01, float& r10, float& r11, float& r20, float& r21)
{
    const float4* W0 = reinterpret_cast<const float4*>(wr0);
    const float4* W1 = reinterpret_cast<const float4*>(wr1);
    const float4* W2 = reinterpret_cast<const float4*>(wr2);
    const float4* X0 = reinterpret_cast<const float4*>(x0);
    const float4* X1 = reinterpret_cast<const float4*>(x1);
    float a00 = 0.f, a01 = 0.f, a10 = 0.f, a11 = 0.f, a20 = 0.f, a21 = 0.f;
    #pragma unroll 4
    for (int c = 0; c < C4; ++c) {
        float4 u0 = W0[c], u1 = W1[c], u2 = W2[c];
        float4 v0 = X0[c], v1 = X1[c];
        a00 = fmaf(u0.x, v0.x, a00); a00 = fmaf(u0.y, v0.y, a00); a00 = fmaf(u0.z, v0.z, a00); a00 = fmaf(u0.w, v0.w, a00);
        a01 = fmaf(u0.x, v1.x, a01); a01 = fmaf(u0.y, v1.y, a01); a01 = fmaf(u0.z, v1.z, a01); a01 = fmaf(u0.w, v1.w, a01);
        a10 = fmaf(u1.x, v0.x, a10); a10 = fmaf(u1.y, v0.y, a10); a10 = fmaf(u1.z, v0.z, a10); a10 = fmaf(u1.w, v0.w, a10);
        a11 = fmaf(u1.x, v1.x, a11); a11 = fmaf(u1.y, v1.y, a11); a11 = fmaf(u1.z, v1.z, a11); a11 = fmaf(u1.w, v1.w, a11);
        a20 = fmaf(u2.x, v0.x, a20); a20 = fmaf(u2.y, v0.y, a20); a20 = fmaf(u2.z, v0.z, a20); a20 = fmaf(u2.w, v0.w, a20);
        a21 = fmaf(u2.x, v1.x, a21); a21 = fmaf(u2.y, v1.y, a21); a21 = fmaf(u2.z, v1.z, a21); a21 = fmaf(u2.w, v1.w, a21);
    }
    r00 = a00; r01 = a01; r10 = a10; r11 = a11; r20 = a20; r21 = a21;
}

// f32 dot of one weight row against TWO LDS vectors (pfc1) — R9 chain.
template<int C4>
__device__ __forceinline__ void dot2f(const float* __restrict__ w,
        const float* __restrict__ x0, const float* __restrict__ x1, float& r0, float& r1)
{
    const float4* W = reinterpret_cast<const float4*>(w);
    float a0 = 0.f, a1 = 0.f;
    #pragma unroll 8
    for (int c = 0; c < C4; ++c) {
        float4 u = W[c];
        int k = 4 * c;
        a0 = fmaf(u.x, x0[k], a0); a0 = fmaf(u.y, x0[k+1], a0); a0 = fmaf(u.z, x0[k+2], a0); a0 = fmaf(u.w, x0[k+3], a0);
        a1 = fmaf(u.x, x1[k], a1); a1 = fmaf(u.y, x1[k+1], a1); a1 = fmaf(u.z, x1[k+2], a1); a1 = fmaf(u.w, x1[k+3], a1);
    }
    r0 = a0; r1 = a1;
}

// Single-vector variant, same per-accumulator chain (pfc2).
template<int C4>
__device__ __forceinline__ void dot1f(const float* __restrict__ w,
        const float* __restrict__ x0, float& r0)
{
    const float4* W = reinterpret_cast<const float4*>(w);
    float a0 = 0.f;
    #pragma unroll 8
    for (int c = 0; c < C4; ++c) {
        float4 u = W[c];
        int k = 4 * c;
        a0 = fmaf(u.x, x0[k], a0); a0 = fmaf(u.y, x0[k+1], a0); a0 = fmaf(u.z, x0[k+2], a0); a0 = fmaf(u.w, x0[k+3], a0);
    }
    r0 = a0;
}

// f64-accum dot of an f32 row vs f32 LDS vector (mu/lv epilogue) — R9 verbatim.
template<int C4>
__device__ __forceinline__ double dotwd(const float* __restrict__ w, const float* __restrict__ x)
{
    const float4* W = reinterpret_cast<const float4*>(w);
    double a = 0.0;
    #pragma unroll 8
    for (int c = 0; c < C4; ++c) {
        float4 u = W[c];
        const float* p = x + 4 * c;
        a = fma((double)u.x, (double)p[0], a);
        a = fma((double)u.y, (double)p[1], a);
        a = fma((double)u.z, (double)p[2], a);
        a = fma((double)u.w, (double)p[3], a);
    }
    return a;
}

// GRU nonlinearity (f64 internals, f32 storage) — R9 verbatim.
__device__ __forceinline__ void gruc(const float* __restrict__ bih, const float* __restrict__ bhh,
        const float* __restrict__ pa, const float* __restrict__ pb, float* __restrict__ h, int j)
{
    double r = 1.0 / (1.0 + exp(-(((double)pa[j]        + (double)bih[j])        + ((double)pb[j]        + (double)bhh[j]))));
    double z = 1.0 / (1.0 + exp(-(((double)pa[NH + j]   + (double)bih[NH + j])   + ((double)pb[NH + j]   + (double)bhh[NH + j]))));
    double n = tanh(((double)pa[2*NH + j] + (double)bih[2*NH + j]) + r * ((double)pb[2*NH + j] + (double)bhh[2*NH + j]));
    h[j] = (float)((1.0 - z) * n + z * (double)h[j]);
}

__global__ __launch_bounds__(NTHR) void vae_v13(
    const float* __restrict__ instance, const int* __restrict__ sol1,
    const int* __restrict__ sol2, const float* __restrict__ eps,
    const float* __restrict__ emb_i_W, const float* __restrict__ emb_i_b,
    const float* __restrict__ emb_r_W, const float* __restrict__ emb_r_b,
    const float* __restrict__ attn_W, const float* __restrict__ attn_v,
    const float* __restrict__ gru_Wih, const float* __restrict__ gru_Whh,
    const float* __restrict__ gru_bih, const float* __restrict__ gru_bhh,
    const float* __restrict__ grud_Wih, const float* __restrict__ grud_Whh,
    const float* __restrict__ grud_bih, const float* __restrict__ grud_bhh,
    const float* __restrict__ efc1_W, const float* __restrict__ efc1_b,
    const float* __restrict__ efc2_W, const float* __restrict__ efc2_b,
    const float* __restrict__ ptr_W, const float* __restrict__ ptr_v,
    const float* __restrict__ pfc1_W, const float* __restrict__ pfc1_b,
    const float* __restrict__ pfc2_W, const float* __restrict__ pfc2_b,
    float* __restrict__ out)
{
    __shared__ float  s_x[GPB][360];            // enc: [ref|ctx]; dec: [ctx|Z|ref]
    __shared__ float  s_h1[GPB][NH], s_h2[GPB][NH], s_fco[GPB][NH];
    __shared__ float  s_fch[GPB][256];
    __shared__ float  s_pa[GPB][3 * NH], s_pb[GPB][3 * NH];
    __shared__ double s_qh[GPB][NH];            // Ab + rnn-side q (f64)
    __shared__ double2 dAa[NH], dAp[NH];        // packed (A0,A1) collapse tables (f64)
    __shared__ double dAba[NH], dAbp[NH];       // bias collapse (f64)
    __shared__ float  s_lg[GPB][NS], s_a[GPB][NS];
    __shared__ float  s_c0[GPB][NS], s_c1[GPB][NS], s_msk[GPB][NS];
    __shared__ float  t_wi0[NH], t_wi1[NH], t_bi[NH];
    __shared__ float  t_wr0[NH], t_wr1[NH], t_br[NH];
    __shared__ float  t_va[NH], t_vp[NH];
    __shared__ float  s_red[GPB][16];           // f32 max partials
    __shared__ double s_redd[GPB][16];          // f64 sum partials
    __shared__ int    s_ri[GPB][16];
    __shared__ float  s_mx[GPB];
    __shared__ double s_se[GPB];
    __shared__ float  s_rc0[GPB], s_rc1[GPB];

    const int tid = threadIdx.x;
    const int bbase = blockIdx.x * GPB;
    const int j = tid & (NH - 1);
    const int half = tid >> 7;
    const int g = half;                 // this thread's batch group for elementwise phases

    // ---------- init ----------
    if (tid < NH) {
        t_wi0[tid] = emb_i_W[2*tid]; t_wi1[tid] = emb_i_W[2*tid+1]; t_bi[tid] = emb_i_b[tid];
        t_wr0[tid] = emb_r_W[2*tid]; t_wr1[tid] = emb_r_W[2*tid+1]; t_br[tid] = emb_r_b[tid];
        t_va[tid] = attn_v[tid]; t_vp[tid] = ptr_v[tid];
    }
    for (int i = tid; i < GPB * NS; i += NTHR) {
        int gg = i / NS, s = i - gg * NS;
        s_c0[gg][s] = instance[(size_t)((bbase + gg) * NS + s) * 2 + 0];
        s_c1[gg][s] = instance[(size_t)((bbase + gg) * NS + s) * 2 + 1];
    }
    s_h1[g][j] = 0.f;
    s_h2[g][j] = 0.f;
    __syncthreads();
    {   // collapse tables: f64 exact algebra (R9 verbatim), packed write
        const float* Wm = (half == 0) ? attn_W : ptr_W;
        double a0 = 0.0, a1 = 0.0, ab = 0.0;
        for (int k = 0; k < NH; ++k) {
            double wv = (double)Wm[(size_t)k * NH + j];
            a0 = fma((double)t_wi0[k], wv, a0);
            a1 = fma((double)t_wi1[k], wv, a1);
            ab = fma((double)t_bi[k],  wv, ab);
        }
        if (half == 0) { dAa[j].x = a0; dAa[j].y = a1; dAba[j] = ab; }
        else           { dAp[j].x = a0; dAp[j].y = a1; dAbp[j] = ab; }
    }
    {   // initial encoder ref_h
        int sp = sol1[(bbase + g) * NS + 0];
        s_x[g][j] = fmaf(s_c0[g][sp], t_wr0[j], fmaf(s_c1[g][sp], t_wr1[j], t_br[j]));
    }
    __syncthreads();

    // ---------- encoder ----------
    for (int t = 1; t < NS; ++t) {
        if (half == 0) {    // GRU1 x-side: fused 3 rows, x read once
            float a00,a01,a10,a11,a20,a21;
            dot2x3f<32>(gru_Wih + (size_t)j * NH, gru_Wih + (size_t)(NH + j) * NH,
                        gru_Wih + (size_t)(2*NH + j) * NH, s_x[0], s_x[1],
                        a00,a01,a10,a11,a20,a21);
            s_pa[0][j] = a00;        s_pa[1][j] = a01;
            s_pa[0][NH + j] = a10;   s_pa[1][NH + j] = a11;
            s_pa[0][2*NH + j] = a20; s_pa[1][2*NH + j] = a21;
        } else {            // GRU1 h-side
            float a00,a01,a10,a11,a20,a21;
            dot2x3f<32>(gru_Whh + (size_t)j * NH, gru_Whh + (size_t)(NH + j) * NH,
                        gru_Whh + (size_t)(2*NH + j) * NH, s_h1[0], s_h1[1],
                        a00,a01,a10,a11,a20,a21);
            s_pb[0][j] = a00;        s_pb[1][j] = a01;
            s_pb[0][NH + j] = a10;   s_pb[1][NH + j] = a11;
            s_pb[0][2*NH + j] = a20; s_pb[1][2*NH + j] = a21;
        }
        __syncthreads();
        gruc(gru_bih, gru_bhh, s_pa[g], s_pb[g], s_h1[g], j);
        __syncthreads();
        {   // q = Ab + h1 . attn_W[128:256] cols (f64, 4-way split chains)
            const float* col = attn_W + (size_t)NH * NH + j;
            double a0 = 0.0, a1 = 0.0, a2 = 0.0, a3 = 0.0;
            #pragma unroll 4
            for (int k = 0; k < NH; k += 4) {
                a0 = fma((double)col[(size_t)(k+0) * NH], (double)s_h1[g][k+0], a0);
                a1 = fma((double)col[(size_t)(k+1) * NH], (double)s_h1[g][k+1], a1);
                a2 = fma((double)col[(size_t)(k+2) * NH], (double)s_h1[g][k+2], a2);
                a3 = fma((double)col[(size_t)(k+3) * NH], (double)s_h1[g][k+3], a3);
            }
            s_qh[g][j] = dAba[j] + ((a0 + a1) + (a2 + a3));
        }
        __syncthreads();
        if (j < NS) {   // relu head logits (f64, 4-way split chains)
            double c00 = (double)s_c0[g][j], c10 = (double)s_c1[g][j];
            double acc0 = 0.0, acc1 = 0.0, acc2 = 0.0, acc3 = 0.0;
            #pragma unroll 4
            for (int h = 0; h < NH; h += 4) {
                double2 A0 = dAa[h+0], A1 = dAa[h+1], A2 = dAa[h+2], A3 = dAa[h+3];
                double p0 = fma(c00, A0.x, fma(c10, A0.y, s_qh[g][h+0]));
                double p1 = fma(c00, A1.x, fma(c10, A1.y, s_qh[g][h+1]));
                double p2 = fma(c00, A2.x, fma(c10, A2.y, s_qh[g][h+2]));
                double p3 = fma(c00, A3.x, fma(c10, A3.y, s_qh[g][h+3]));
                acc0 = fma(fmax(p0, 0.0), (double)t_va[h+0], acc0);
                acc1 = fma(fmax(p1, 0.0), (double)t_va[h+1], acc1);
                acc2 = fma(fmax(p2, 0.0), (double)t_va[h+2], acc2);
                acc3 = fma(fmax(p3, 0.0), (double)t_va[h+3], acc3);
            }
            s_lg[g][j] = (float)(((acc0 + acc1) + (acc2 + acc3)));
        }
        __syncthreads();
        if (j < 16) {   // segmented max (exact, order-free)
            float m0 = NEGF;
            for (int s = j; s < NS; s += 16) m0 = fmaxf(m0, s_lg[g][s]);
            s_red[g][j] = m0;
        }
        __syncthreads();
        if (tid < GPB) {
            float m = NEGF;
            for (int i = 0; i < 16; ++i) m = fmaxf(m, s_red[tid][i]);
            s_mx[tid] = m;
        }
        __syncthreads();
        if (j < NS) {   // exps: f64 exp narrowed to f32 (R9 semantics)
            s_a[g][j] = (float)exp((double)s_lg[g][j] - (double)s_mx[g]);
        }
        __syncthreads();
        if (j < 16) {   // segmented f64 sum
            double t0 = 0.0;
            for (int s = j; s < NS; s += 16) t0 += (double)s_a[g][s];
            s_redd[g][j] = t0;
        }
        __syncthreads();
        if (tid < GPB) {
            double se = 0.0;
            for (int i = 0; i < 16; ++i) se += s_redd[tid][i];
            s_se[tid] = se;
        }
        __syncthreads();
        if (j < NS) {   // normalize first (R9 semantics)
            s_a[g][j] = (float)((double)s_a[g][j] / s_se[g]);
        }
        __syncthreads();
        {   // context (f64, 4-way split chains) + new ref_h
            float w0 = t_wi0[j], w1 = t_wi1[j], bb = t_bi[j];
            double a0 = 0.0, a1 = 0.0, a2 = 0.0, a3 = 0.0;
            #pragma unroll 5
            for (int s = 0; s < NS; s += 4) {
                float ih0 = fmaf(s_c0[g][s+0], w0, fmaf(s_c1[g][s+0], w1, bb));
                float ih1 = fmaf(s_c0[g][s+1], w0, fmaf(s_c1[g][s+1], w1, bb));
                float ih2 = fmaf(s_c0[g][s+2], w0, fmaf(s_c1[g][s+2], w1, bb));
                float ih3 = fmaf(s_c0[g][s+3], w0, fmaf(s_c1[g][s+3], w1, bb));
                a0 += (double)s_a[g][s+0] * (double)ih0;
                a1 += (double)s_a[g][s+1] * (double)ih1;
                a2 += (double)s_a[g][s+2] * (double)ih2;
                a3 += (double)s_a[g][s+3] * (double)ih3;
            }
            s_x[g][NH + j] = (float)(((a0 + a1) + (a2 + a3)));
            int sp = sol1[(bbase + g) * NS + t];
            s_x[g][j] = fmaf(s_c0[g][sp], t_wr0[j], fmaf(s_c1[g][sp], t_wr1[j], t_br[j]));
        }
        __syncthreads();
        if (half == 0) {    // GRUd x-side (K=256), fused 3 rows
            float a00,a01,a10,a11,a20,a21;
            dot2x3f<64>(grud_Wih + (size_t)j * 256, grud_Wih + (size_t)(NH + j) * 256,
                        grud_Wih + (size_t)(2*NH + j) * 256, s_x[0], s_x[1],
                        a00,a01,a10,a11,a20,a21);
            s_pa[0][j] = a00;        s_pa[1][j] = a01;
            s_pa[0][NH + j] = a10;   s_pa[1][NH + j] = a11;
            s_pa[0][2*NH + j] = a20; s_pa[1][2*NH + j] = a21;
        } else {            // GRUd h-side, fused 3 rows
            float a00,a01,a10,a11,a20,a21;
            dot2x3f<32>(grud_Whh + (size_t)j * NH, grud_Whh + (size_t)(NH + j) * NH,
                        grud_Whh + (size_t)(2*NH + j) * NH, s_h2[0], s_h2[1],
                        a00,a01,a10,a11,a20,a21);
            s_pb[0][j] = a00;        s_pb[1][j] = a01;
            s_pb[0][NH + j] = a10;   s_pb[1][NH + j] = a11;
            s_pb[0][2*NH + j] = a20; s_pb[1][2*NH + j] = a21;
        }
        __syncthreads();
        gruc(grud_bih, grud_bhh, s_pa[g], s_pb[g], s_h2[g], j);
        __syncthreads();
    }

    // ---------- epilogue: mu, lv, Z (f64, R9 verbatim) ----------
    for (int idx = tid; idx < GPB * NS; idx += NTHR) {
        int gg = idx / NS, s = idx - gg * NS, b = bbase + gg;
        double mu = dotwd<32>(efc1_W + (size_t)s * NH, s_h2[gg]) + (double)efc1_b[s];
        double lv = dotwd<32>(efc2_W + (size_t)s * NH, s_h2[gg]) + (double)efc2_b[s];
        double z  = mu + (double)eps[(size_t)b * NS + s] * exp(0.5 * lv);
        out[OUT_MU + b * NS + s] = (float)mu;
        out[OUT_LV + b * NS + s] = (float)lv;
        out[OUT_Z  + b * NS + s] = (float)z;
        s_x[gg][NH + s] = (float)z;   // decoder Z slot [128..227]
    }
    for (int i = tid; i < GPB * NS; i += NTHR) {
        int gg = i / NS, s = i - gg * NS;
        s_msk[gg][s] = 1.f;
    }
    s_h1[g][j] = 0.f;
    __syncthreads();
    if (tid < GPB) {
        int b = bbase + tid;
        int s0 = sol2[b * NS + 0];
        s_msk[tid][s0] = 0.f;
        s_rc0[tid] = s_c0[tid][s0];
        s_rc1[tid] = s_c1[tid][s0];
        out[OUT_TI + b * NS + 0] = (float)s0;
    }
    __syncthreads();

    // ---------- decoder ----------
    for (int t = 1; t < NS; ++t) {
        s_x[g][228 + j] = fmaf(s_rc0[g], t_wr0[j], fmaf(s_rc1[g], t_wr1[j], t_br[j]));
        __syncthreads();
        if (half == 0) {    // GRU1 x-side on ref, fused 3 rows
            float a00,a01,a10,a11,a20,a21;
            dot2x3f<32>(gru_Wih + (size_t)j * NH, gru_Wih + (size_t)(NH + j) * NH,
                        gru_Wih + (size_t)(2*NH + j) * NH, s_x[0]+228, s_x[1]+228,
                        a00,a01,a10,a11,a20,a21);
            s_pa[0][j] = a00;        s_pa[1][j] = a01;
            s_pa[0][NH + j] = a10;   s_pa[1][NH + j] = a11;
            s_pa[0][2*NH + j] = a20; s_pa[1][2*NH + j] = a21;
        } else {
            float a00,a01,a10,a11,a20,a21;
            dot2x3f<32>(gru_Whh + (size_t)j * NH, gru_Whh + (size_t)(NH + j) * NH,
                        gru_Whh + (size_t)(2*NH + j) * NH, s_h1[0], s_h1[1],
                        a00,a01,a10,a11,a20,a21);
            s_pb[0][j] = a00;        s_pb[1][j] = a01;
            s_pb[0][NH + j] = a10;   s_pb[1][NH + j] = a11;
            s_pb[0][2*NH + j] = a20; s_pb[1][2*NH + j] = a21;
        }
        __syncthreads();
        gruc(gru_bih, gru_bhh, s_pa[g], s_pb[g], s_h1[g], j);
        __syncthreads();
        {   // q (attn, f64, split chains)
            const float* col = attn_W + (size_t)NH * NH + j;
            double a0 = 0.0, a1 = 0.0, a2 = 0.0, a3 = 0.0;
            #pragma unroll 4
            for (int k = 0; k < NH; k += 4) {
                a0 = fma((double)col[(size_t)(k+0) * NH], (double)s_h1[g][k+0], a0);
                a1 = fma((double)col[(size_t)(k+1) * NH], (double)s_h1[g][k+1], a1);
                a2 = fma((double)col[(size_t)(k+2) * NH], (double)s_h1[g][k+2], a2);
                a3 = fma((double)col[(size_t)(k+3) * NH], (double)s_h1[g][k+3], a3);
            }
            s_qh[g][j] = dAba[j] + ((a0 + a1) + (a2 + a3));
        }
        __syncthreads();
        if (j < NS) {   // relu head (f64, split chains)
            double c00 = (double)s_c0[g][j], c10 = (double)s_c1[g][j];
            double acc0 = 0.0, acc1 = 0.0, acc2 = 0.0, acc3 = 0.0;
            #pragma unroll 4
            for (int h = 0; h < NH; h += 4) {
                double2 A0 = dAa[h+0], A1 = dAa[h+1], A2 = dAa[h+2], A3 = dAa[h+3];
                double p0 = fma(c00, A0.x, fma(c10, A0.y, s_qh[g][h+0]));
                double p1 = fma(c00, A1.x, fma(c10, A1.y, s_qh[g][h+1]));
                double p2 = fma(c00, A2.x, fma(c10, A2.y, s_qh[g][h+2]));
                double p3 = fma(c00, A3.x, fma(c10, A3.y, s_qh[g][h+3]));
                acc0 = fma(fmax(p0, 0.0), (double)t_va[h+0], acc0);
                acc1 = fma(fmax(p1, 0.0), (double)t_va[h+1], acc1);
                acc2 = fma(fmax(p2, 0.0), (double)t_va[h+2], acc2);
                acc3 = fma(fmax(p3, 0.0), (double)t_va[h+3], acc3);
            }
            s_lg[g][j] = (float)(((acc0 + acc1) + (acc2 + acc3)));
        }
        __syncthreads();
        if (j < 16) {
            float m0 = NEGF;
            for (int s = j; s < NS; s += 16) m0 = fmaxf(m0, s_lg[g][s]);
            s_red[g][j] = m0;
        }
        __syncthreads();
        if (tid < GPB) {
            float m = NEGF;
            for (int i = 0; i < 16; ++i) m = fmaxf(m, s_red[tid][i]);
            s_mx[tid] = m;
        }
        __syncthreads();
        if (j < NS) {
            s_a[g][j] = (float)exp((double)s_lg[g][j] - (double)s_mx[g]);
        }
        __syncthreads();
        if (j < 16) {
            double t0 = 0.0;
            for (int s = j; s < NS; s += 16) t0 += (double)s_a[g][s];
            s_redd[g][j] = t0;
        }
        __syncthreads();
        if (tid < GPB) {
            double se = 0.0;
            for (int i = 0; i < 16; ++i) se += s_redd[tid][i];
            s_se[tid] = se;
        }
        __syncthreads();
        if (j < NS) {
            s_a[g][j] = (float)((double)s_a[g][j] / s_se[g]);
        }
        __syncthreads();
        {   // context -> s_x[g][0..127] (f64, split chains)
            float w0 = t_wi0[j], w1 = t_wi1[j], bb = t_bi[j];
            double a0 = 0.0, a1 = 0.0, a2 = 0.0, a3 = 0.0;
            #pragma unroll 5
            for (int s = 0; s < NS; s += 4) {
                float ih0 = fmaf(s_c0[g][s+0], w0, fmaf(s_c1[g][s+0], w1, bb));
                float ih1 = fmaf(s_c0[g][s+1], w0, fmaf(s_c1[g][s+1], w1, bb));
                float ih2 = fmaf(s_c0[g][s+2], w0, fmaf(s_c1[g][s+2], w1, bb));
                float ih3 = fmaf(s_c0[g][s+3], w0, fmaf(s_c1[g][s+3], w1, bb));
                a0 += (double)s_a[g][s+0] * (double)ih0;
                a1 += (double)s_a[g][s+1] * (double)ih1;
                a2 += (double)s_a[g][s+2] * (double)ih2;
                a3 += (double)s_a[g][s+3] * (double)ih3;
            }
            s_x[g][j] = (float)(((a0 + a1) + (a2 + a3)));
        }
        __syncthreads();
        {   // pfc1: row i = tid, one read -> 2 batches (f32, R9 chain)
            float r0, r1;
            dot2f<89>(pfc1_W + (size_t)tid * 356, s_x[0], s_x[1], r0, r1);
            float bb = pfc1_b[tid];
            s_fch[0][tid] = r0 + bb; s_fch[1][tid] = r1 + bb;
        }
        __syncthreads();
        {   // pfc2 (f32)
            float r0;
            dot1f<64>(pfc2_W + (size_t)j * 256, s_fch[g], r0);
            s_fco[g][j] = r0 + pfc2_b[j];
        }
        __syncthreads();
        {   // q2 (ptr, f64, split chains)
            const float* col = ptr_W + (size_t)NH * NH + j;
            double a0 = 0.0, a1 = 0.0, a2 = 0.0, a3 = 0.0;
            #pragma unroll 4
            for (int k = 0; k < NH; k += 4) {
                a0 = fma((double)col[(size_t)(k+0) * NH], (double)s_fco[g][k+0], a0);
                a1 = fma((double)col[(size_t)(k+1) * NH], (double)s_fco[g][k+1], a1);
                a2 = fma((double)col[(size_t)(k+2) * NH], (double)s_fco[g][k+2], a2);
                a3 = fma((double)col[(size_t)(k+3) * NH], (double)s_fco[g][k+3], a3);
            }
            s_qh[g][j] = dAbp[j] + ((a0 + a1) + (a2 + a3));
        }
        __syncthreads();
        if (j < NS) {   // tanh pointer head (f64 pre, tanhf, split chains)
            double c00 = (double)s_c0[g][j], c10 = (double)s_c1[g][j];
            double acc0 = 0.0, acc1 = 0.0, acc2 = 0.0, acc3 = 0.0;
            #pragma unroll 4
            for (int h = 0; h < NH; h += 4) {
                double2 A0 = dAp[h+0], A1 = dAp[h+1], A2 = dAp[h+2], A3 = dAp[h+3];
                double p0 = fma(c00, A0.x, fma(c10, A0.y, s_qh[g][h+0]));
                double p1 = fma(c00, A1.x, fma(c10, A1.y, s_qh[g][h+1]));
                double p2 = fma(c00, A2.x, fma(c10, A2.y, s_qh[g][h+2]));
                double p3 = fma(c00, A3.x, fma(c10, A3.y, s_qh[g][h+3]));
                acc0 = fma((double)tanhf((float)p0), (double)t_vp[h+0], acc0);
                acc1 = fma((double)tanhf((float)p1), (double)t_vp[h+1], acc1);
                acc2 = fma((double)tanhf((float)p2), (double)t_vp[h+2], acc2);
                acc3 = fma((double)tanhf((float)p3), (double)t_vp[h+3], acc3);
            }
            s_lg[g][j] = (float)(((acc0 + acc1) + (acc2 + acc3)));
        }
        __syncthreads();
        if (j < 16) {   // masked segmented max of logits (for exp stability only)
            float m0 = NEGF;
            for (int s = j; s < NS; s += 16) {
                float v0 = (s_msk[g][s] > 0.f) ? s_lg[g][s] : NEGF;
                m0 = fmaxf(m0, v0);
            }
            s_red[g][j] = m0;
        }
        __syncthreads();
        if (tid < GPB) {
            float m = NEGF;
            for (int i = 0; i < 16; ++i) m = fmaxf(m, s_red[tid][i]);
            s_mx[tid] = m;
        }
        __syncthreads();
        if (j < NS) {   // masked exps, f64 exp narrowed to f32 (R9 semantics)
            s_a[g][j] = (s_msk[g][j] > 0.f) ? (float)exp((double)s_lg[g][j] - (double)s_mx[g]) : 0.f;
        }
        __syncthreads();
        if (j < 16) {   // argmax over f32 EXPS (prob-equivalent), first-occurrence ties
            float m0 = -1.f; int i0 = 0;
            double t0 = 0.0;
            for (int s = j; s < NS; s += 16) {
                float a0v = s_a[g][s];
                t0 += (double)a0v;
                if (a0v > m0) { m0 = a0v; i0 = s; }
            }
            s_red[g][j] = m0; s_ri[g][j] = i0; s_redd[g][j] = t0;
        }
        __syncthreads();
        if (tid < GPB) {   // fold: first-occurrence argmax + se; outputs + carry
            int gg = tid, b = bbase + gg;
            float m = -1.f; int mi = NS; double se = 0.0;
            for (int i = 0; i < 16; ++i) {
                se += s_redd[gg][i];
                float v = s_red[gg][i]; int vi = s_ri[gg][i];
                if (v > m || (v == m && vi < mi)) { m = v; mi = vi; }
            }
            int pt = sol2[b * NS + t];
            double logp = log((double)s_a[gg][pt] / se);
            out[OUT_TI + b * NS + t]             = (float)mi;
            out[OUT_LP + b * (NS - 1) + (t - 1)] = (float)logp;
            s_msk[gg][pt] = 0.f;
            s_rc0[gg] = s_c0[gg][pt];
            s_rc1[gg] = s_c1[gg][pt];
        }
        __syncthreads();
    }
}

extern "C" void kernel_launch(void* const* d_in, const int* in_sizes, int n_in,
                              void* d_out, int out_size, void* d_ws, size_t ws_size,
                              hipStream_t stream)
{
    (void)in_sizes; (void)n_in; (void)out_size; (void)d_ws; (void)ws_size;
    vae_v13<<<NBLK, NTHR, 0, stream>>>(
        (const float*)d_in[0], (const int*)d_in[1], (const int*)d_in[2], (const float*)d_in[3],
        (const float*)d_in[4], (const float*)d_in[5], (const float*)d_in[6], (const float*)d_in[7],
        (const float*)d_in[8], (const float*)d_in[9], (const float*)d_in[10], (const float*)d_in[11],
        (const float*)d_in[12], (const float*)d_in[13], (const float*)d_in[14], (const float*)d_in[15],
        (const float*)d_in[16], (const float*)d_in[17], (const float*)d_in[18], (const float*)d_in[19],
        (const float*)d_in[20], (const float*)d_in[21], (const float*)d_in[22], (const float*)d_in[23],
        (const float*)d_in[24], (const float*)d_in[25], (const float*)d_in[26], (const float*)d_in[27],
        (float*)d_out);
}

// Round 3
// 12260.564 us; speedup vs baseline: 1.1544x; 1.0373x over previous
//
#include <hip/hip_runtime.h>
#include <math.h>

static constexpr int NB  = 1024;
static constexpr int NS  = 100;
static constexpr int NH  = 128;
static constexpr int GPB = 2;           // batches per block
static constexpr int NTHR = 256;
static constexpr int NBLK = NB / GPB;   // 512 blocks, all co-resident (2/CU)

static constexpr int OUT_MU = 0;
static constexpr int OUT_LV = NB * NS;
static constexpr int OUT_Z  = 2 * NB * NS;
static constexpr int OUT_TI = 3 * NB * NS;
static constexpr int OUT_LP = 4 * NB * NS;

#define NEGF (-3.4e38f)

// Fused 3-row x 2-batch f32 dot: X read as float4 (once), 3 weight rows.
// Per-accumulator fmaf chain is k-ascending — bitwise identical to R9 chains.
template<int C4>
__device__ __forceinline__ void dot2x3f(const float* __restrict__ wr0,
        const float* __restrict__ wr1, const float* __restrict__ wr2,
        const float* __restrict__ x0, const float* __restrict__ x1,
        float& r00, float& r01, float& r10, float& r11, float& r20, float& r21)
{
    const float4* W0 = reinterpret_cast<const float4*>(wr0);
    const float4* W1 = reinterpret_cast<const float4*>(wr1);
    const float4* W2 = reinterpret_cast<const float4*>(wr2);
    const float4* X0 = reinterpret_cast<const float4*>(x0);
    const float4* X1 = reinterpret_cast<const float4*>(x1);
    float a00 = 0.f, a01 = 0.f, a10 = 0.f, a11 = 0.f, a20 = 0.f, a21 = 0.f;
    #pragma unroll 8
    for (int c = 0; c < C4; ++c) {
        float4 u0 = W0[c], u1 = W1[c], u2 = W2[c];
        float4 v0 = X0[c], v1 = X1[c];
        a00 = fmaf(u0.x, v0.x, a00); a00 = fmaf(u0.y, v0.y, a00); a00 = fmaf(u0.z, v0.z, a00); a00 = fmaf(u0.w, v0.w, a00);
        a01 = fmaf(u0.x, v1.x, a01); a01 = fmaf(u0.y, v1.y, a01); a01 = fmaf(u0.z, v1.z, a01); a01 = fmaf(u0.w, v1.w, a01);
        a10 = fmaf(u1.x, v0.x, a10); a10 = fmaf(u1.y, v0.y, a10); a10 = fmaf(u1.z, v0.z, a10); a10 = fmaf(u1.w, v0.w, a10);
        a11 = fmaf(u1.x, v1.x, a11); a11 = fmaf(u1.y, v1.y, a11); a11 = fmaf(u1.z, v1.z, a11); a11 = fmaf(u1.w, v1.w, a11);
        a20 = fmaf(u2.x, v0.x, a20); a20 = fmaf(u2.y, v0.y, a20); a20 = fmaf(u2.z, v0.z, a20); a20 = fmaf(u2.w, v0.w, a20);
        a21 = fmaf(u2.x, v1.x, a21); a21 = fmaf(u2.y, v1.y, a21); a21 = fmaf(u2.z, v1.z, a21); a21 = fmaf(u2.w, v1.w, a21);
    }
    r00 = a00; r01 = a01; r10 = a10; r11 = a11; r20 = a20; r21 = a21;
}

// One weight row vs TWO LDS vectors (pfc1) — same per-acc chain, X as float4.
template<int C4>
__device__ __forceinline__ void dot2f(const float* __restrict__ w,
        const float* __restrict__ x0, const float* __restrict__ x1, float& r0, float& r1)
{
    const float4* W = reinterpret_cast<const float4*>(w);
    const float4* X0 = reinterpret_cast<const float4*>(x0);
    const float4* X1 = reinterpret_cast<const float4*>(x1);
    float a0 = 0.f, a1 = 0.f;
    #pragma unroll 8
    for (int c = 0; c < C4; ++c) {
        float4 u = W[c];
        float4 v0 = X0[c], v1 = X1[c];
        a0 = fmaf(u.x, v0.x, a0); a0 = fmaf(u.y, v0.y, a0); a0 = fmaf(u.z, v0.z, a0); a0 = fmaf(u.w, v0.w, a0);
        a1 = fmaf(u.x, v1.x, a1); a1 = fmaf(u.y, v1.y, a1); a1 = fmaf(u.z, v1.z, a1); a1 = fmaf(u.w, v1.w, a1);
    }
    r0 = a0; r1 = a1;
}

template<int C4>
__device__ __forceinline__ void dot1f(const float* __restrict__ w,
        const float* __restrict__ x0, float& r0)
{
    const float4* W = reinterpret_cast<const float4*>(w);
    const float4* X0 = reinterpret_cast<const float4*>(x0);
    float a0 = 0.f;
    #pragma unroll 8
    for (int c = 0; c < C4; ++c) {
        float4 u = W[c];
        float4 v0 = X0[c];
        a0 = fmaf(u.x, v0.x, a0); a0 = fmaf(u.y, v0.y, a0); a0 = fmaf(u.z, v0.z, a0); a0 = fmaf(u.w, v0.w, a0);
    }
    r0 = a0;
}

// f64-accum dot (mu/lv epilogue) — R9 verbatim.
template<int C4>
__device__ __forceinline__ double dotwd(const float* __restrict__ w, const float* __restrict__ x)
{
    const float4* W = reinterpret_cast<const float4*>(w);
    double a = 0.0;
    #pragma unroll 8
    for (int c = 0; c < C4; ++c) {
        float4 u = W[c];
        const float* p = x + 4 * c;
        a = fma((double)u.x, (double)p[0], a);
        a = fma((double)u.y, (double)p[1], a);
        a = fma((double)u.z, (double)p[2], a);
        a = fma((double)u.w, (double)p[3], a);
    }
    return a;
}

// GRU nonlinearity (f64 internals, f32 storage) — R9 verbatim (biases now from LDS).
__device__ __forceinline__ void gruc(const float* __restrict__ bih, const float* __restrict__ bhh,
        const float* __restrict__ pa, const float* __restrict__ pb, float* __restrict__ h, int j)
{
    double r = 1.0 / (1.0 + exp(-(((double)pa[j]        + (double)bih[j])        + ((double)pb[j]        + (double)bhh[j]))));
    double z = 1.0 / (1.0 + exp(-(((double)pa[NH + j]   + (double)bih[NH + j])   + ((double)pb[NH + j]   + (double)bhh[NH + j]))));
    double n = tanh(((double)pa[2*NH + j] + (double)bih[2*NH + j]) + r * ((double)pb[2*NH + j] + (double)bhh[2*NH + j]));
    h[j] = (float)((1.0 - z) * n + z * (double)h[j]);
}

__global__ __launch_bounds__(NTHR) void vae_v14(
    const float* __restrict__ instance, const int* __restrict__ sol1,
    const int* __restrict__ sol2, const float* __restrict__ eps,
    const float* __restrict__ emb_i_W, const float* __restrict__ emb_i_b,
    const float* __restrict__ emb_r_W, const float* __restrict__ emb_r_b,
    const float* __restrict__ attn_W, const float* __restrict__ attn_v,
    const float* __restrict__ gru_Wih, const float* __restrict__ gru_Whh,
    const float* __restrict__ gru_bih, const float* __restrict__ gru_bhh,
    const float* __restrict__ grud_Wih, const float* __restrict__ grud_Whh,
    const float* __restrict__ grud_bih, const float* __restrict__ grud_bhh,
    const float* __restrict__ efc1_W, const float* __restrict__ efc1_b,
    const float* __restrict__ efc2_W, const float* __restrict__ efc2_b,
    const float* __restrict__ ptr_W, const float* __restrict__ ptr_v,
    const float* __restrict__ pfc1_W, const float* __restrict__ pfc1_b,
    const float* __restrict__ pfc2_W, const float* __restrict__ pfc2_b,
    float* __restrict__ out)
{
    __shared__ float  s_x[GPB][360];            // enc: [ref|ctx]; dec: [ctx|Z|ref]
    __shared__ float  s_h1[GPB][NH], s_h2[GPB][NH], s_fco[GPB][NH];
    __shared__ float  s_fch[GPB][256];
    __shared__ float  s_pa[GPB][3 * NH], s_pb[GPB][3 * NH];
    __shared__ double s_qh[GPB][NH];            // combined q (f64)
    __shared__ double s_qpA[GPB][NH], s_qpB[GPB][NH];  // q k-split partials
    __shared__ double2 dAa[NH], dAp[NH];        // packed (A0,A1) collapse tables (f64)
    __shared__ double dAba[NH], dAbp[NH];       // bias collapse (f64)
    __shared__ float  s_lg[GPB][NS], s_a[GPB][NS];
    __shared__ float  s_c0[GPB][NS], s_c1[GPB][NS], s_msk[GPB][NS];
    __shared__ float  t_wi0[NH], t_wi1[NH], t_bi[NH];
    __shared__ float  t_wr0[NH], t_wr1[NH], t_br[NH];
    __shared__ float  t_va[NH], t_vp[NH];
    __shared__ float  t_gbih[3*NH], t_gbhh[3*NH], t_dbih[3*NH], t_dbhh[3*NH];
    __shared__ float  t_p1b[256], t_p2b[NH];
    __shared__ int    s_sol1[GPB][NS], s_sol2[GPB][NS];
    __shared__ float  s_red[GPB][2];            // wave argmax val candidates
    __shared__ double s_redd[GPB][2];           // wave f64 sum partials
    __shared__ int    s_ri[GPB][2];             // wave argmax idx candidates
    __shared__ float  s_rc0[GPB], s_rc1[GPB];

    const int tid = threadIdx.x;
    const int bbase = blockIdx.x * GPB;
    const int j = tid & (NH - 1);
    const int half = tid >> 7;
    const int g = half;                 // this thread's batch for elementwise phases
    const int lane = tid & 63;
    const int wid = (tid >> 6) & 1;     // wave index within half

    // ---------- init ----------
    if (tid < NH) {
        t_wi0[tid] = emb_i_W[2*tid]; t_wi1[tid] = emb_i_W[2*tid+1]; t_bi[tid] = emb_i_b[tid];
        t_wr0[tid] = emb_r_W[2*tid]; t_wr1[tid] = emb_r_W[2*tid+1]; t_br[tid] = emb_r_b[tid];
        t_va[tid] = attn_v[tid]; t_vp[tid] = ptr_v[tid];
        t_p2b[tid] = pfc2_b[tid];
    }
    t_p1b[tid] = pfc1_b[tid];
    for (int i = tid; i < 3 * NH; i += NTHR) {
        t_gbih[i] = gru_bih[i]; t_gbhh[i] = gru_bhh[i];
        t_dbih[i] = grud_bih[i]; t_dbhh[i] = grud_bhh[i];
    }
    for (int i = tid; i < GPB * NS; i += NTHR) {
        int gg = i / NS, s = i - gg * NS;
        s_c0[gg][s] = instance[(size_t)((bbase + gg) * NS + s) * 2 + 0];
        s_c1[gg][s] = instance[(size_t)((bbase + gg) * NS + s) * 2 + 1];
        s_sol1[gg][s] = sol1[(bbase + gg) * NS + s];
        s_sol2[gg][s] = sol2[(bbase + gg) * NS + s];
    }
    s_h1[g][j] = 0.f;
    s_h2[g][j] = 0.f;
    __syncthreads();
    {   // collapse tables: f64 exact algebra (R9 verbatim), packed write
        const float* Wm = (half == 0) ? attn_W : ptr_W;
        double a0 = 0.0, a1 = 0.0, ab = 0.0;
        for (int k = 0; k < NH; ++k) {
            double wv = (double)Wm[(size_t)k * NH + j];
            a0 = fma((double)t_wi0[k], wv, a0);
            a1 = fma((double)t_wi1[k], wv, a1);
            ab = fma((double)t_bi[k],  wv, ab);
        }
        if (half == 0) { dAa[j].x = a0; dAa[j].y = a1; dAba[j] = ab; }
        else           { dAp[j].x = a0; dAp[j].y = a1; dAbp[j] = ab; }
    }
    {   // initial encoder ref_h
        int sp = s_sol1[g][0];
        s_x[g][j] = fmaf(s_c0[g][sp], t_wr0[j], fmaf(s_c1[g][sp], t_wr1[j], t_br[j]));
    }
    __syncthreads();

    // ---------- encoder ----------
    for (int t = 1; t < NS; ++t) {
        if (half == 0) {    // GRU1 x-side: fused 3 rows
            float a00,a01,a10,a11,a20,a21;
            dot2x3f<32>(gru_Wih + (size_t)j * NH, gru_Wih + (size_t)(NH + j) * NH,
                        gru_Wih + (size_t)(2*NH + j) * NH, s_x[0], s_x[1],
                        a00,a01,a10,a11,a20,a21);
            s_pa[0][j] = a00;        s_pa[1][j] = a01;
            s_pa[0][NH + j] = a10;   s_pa[1][NH + j] = a11;
            s_pa[0][2*NH + j] = a20; s_pa[1][2*NH + j] = a21;
        } else {            // GRU1 h-side
            float a00,a01,a10,a11,a20,a21;
            dot2x3f<32>(gru_Whh + (size_t)j * NH, gru_Whh + (size_t)(NH + j) * NH,
                        gru_Whh + (size_t)(2*NH + j) * NH, s_h1[0], s_h1[1],
                        a00,a01,a10,a11,a20,a21);
            s_pb[0][j] = a00;        s_pb[1][j] = a01;
            s_pb[0][NH + j] = a10;   s_pb[1][NH + j] = a11;
            s_pb[0][2*NH + j] = a20; s_pb[1][2*NH + j] = a21;
        }
        __syncthreads();
        gruc(t_gbih, t_gbhh, s_pa[g], s_pb[g], s_h1[g], j);
        __syncthreads();
        {   // q k-split: thread (half,j) covers 64 k for BOTH batches
            const float* col = attn_W + (size_t)NH * NH + j;
            const int k0 = half * 64;
            double a00=0.0,a01=0.0,a02=0.0,a03=0.0;
            double a10=0.0,a11=0.0,a12=0.0,a13=0.0;
            #pragma unroll 8
            for (int k = 0; k < 64; k += 4) {
                float w0 = col[(size_t)(k0+k+0) * NH];
                float w1 = col[(size_t)(k0+k+1) * NH];
                float w2 = col[(size_t)(k0+k+2) * NH];
                float w3 = col[(size_t)(k0+k+3) * NH];
                float4 h0 = *reinterpret_cast<const float4*>(&s_h1[0][k0+k]);
                float4 h1v = *reinterpret_cast<const float4*>(&s_h1[1][k0+k]);
                a00 = fma((double)w0, (double)h0.x, a00);
                a01 = fma((double)w1, (double)h0.y, a01);
                a02 = fma((double)w2, (double)h0.z, a02);
                a03 = fma((double)w3, (double)h0.w, a03);
                a10 = fma((double)w0, (double)h1v.x, a10);
                a11 = fma((double)w1, (double)h1v.y, a11);
                a12 = fma((double)w2, (double)h1v.z, a12);
                a13 = fma((double)w3, (double)h1v.w, a13);
            }
            if (half == 0) { s_qpA[0][j] = (a00+a01)+(a02+a03); s_qpA[1][j] = (a10+a11)+(a12+a13); }
            else           { s_qpB[0][j] = (a00+a01)+(a02+a03); s_qpB[1][j] = (a10+a11)+(a12+a13); }
        }
        __syncthreads();
        s_qh[g][j] = dAba[j] + (s_qpA[g][j] + s_qpB[g][j]);
        __syncthreads();
        if (j < NS) {   // relu head logits (f64, 4-way split chains)
            double c00 = (double)s_c0[g][j], c10 = (double)s_c1[g][j];
            double acc0 = 0.0, acc1 = 0.0, acc2 = 0.0, acc3 = 0.0;
            #pragma unroll 4
            for (int h = 0; h < NH; h += 4) {
                double2 A0 = dAa[h+0], A1 = dAa[h+1], A2 = dAa[h+2], A3 = dAa[h+3];
                double p0 = fma(c00, A0.x, fma(c10, A0.y, s_qh[g][h+0]));
                double p1 = fma(c00, A1.x, fma(c10, A1.y, s_qh[g][h+1]));
                double p2 = fma(c00, A2.x, fma(c10, A2.y, s_qh[g][h+2]));
                double p3 = fma(c00, A3.x, fma(c10, A3.y, s_qh[g][h+3]));
                acc0 = fma(fmax(p0, 0.0), (double)t_va[h+0], acc0);
                acc1 = fma(fmax(p1, 0.0), (double)t_va[h+1], acc1);
                acc2 = fma(fmax(p2, 0.0), (double)t_va[h+2], acc2);
                acc3 = fma(fmax(p3, 0.0), (double)t_va[h+3], acc3);
            }
            s_lg[g][j] = (float)(((acc0 + acc1) + (acc2 + acc3)));
        }
        __syncthreads();
        {   // fused: wave max (exact) + exp (identical) + wave f64 partial sum
            float a = s_lg[g][lane];
            float b = (lane + 64 < NS) ? s_lg[g][lane + 64] : NEGF;
            float m = fmaxf(a, b);
            m = fmaxf(m, __shfl_xor(m, 32)); m = fmaxf(m, __shfl_xor(m, 16));
            m = fmaxf(m, __shfl_xor(m, 8));  m = fmaxf(m, __shfl_xor(m, 4));
            m = fmaxf(m, __shfl_xor(m, 2));  m = fmaxf(m, __shfl_xor(m, 1));
            float fv = 0.f;
            if (j < NS) { fv = (float)exp((double)s_lg[g][j] - (double)m); s_a[g][j] = fv; }
            double ps = (double)fv;
            ps += __shfl_xor(ps, 32); ps += __shfl_xor(ps, 16);
            ps += __shfl_xor(ps, 8);  ps += __shfl_xor(ps, 4);
            ps += __shfl_xor(ps, 2);  ps += __shfl_xor(ps, 1);
            if (lane == 0) s_redd[g][wid] = ps;
        }
        __syncthreads();
        if (j < NS) {   // normalize (R9 semantics; se = reassoc'd f64 sum)
            double se = s_redd[g][0] + s_redd[g][1];
            s_a[g][j] = (float)((double)s_a[g][j] / se);
        }
        __syncthreads();
        {   // context (f64, 4-way split chains) + new ref_h
            float w0 = t_wi0[j], w1 = t_wi1[j], bb = t_bi[j];
            double a0 = 0.0, a1 = 0.0, a2 = 0.0, a3 = 0.0;
            #pragma unroll 5
            for (int s = 0; s < NS; s += 4) {
                float ih0 = fmaf(s_c0[g][s+0], w0, fmaf(s_c1[g][s+0], w1, bb));
                float ih1 = fmaf(s_c0[g][s+1], w0, fmaf(s_c1[g][s+1], w1, bb));
                float ih2 = fmaf(s_c0[g][s+2], w0, fmaf(s_c1[g][s+2], w1, bb));
                float ih3 = fmaf(s_c0[g][s+3], w0, fmaf(s_c1[g][s+3], w1, bb));
                a0 += (double)s_a[g][s+0] * (double)ih0;
                a1 += (double)s_a[g][s+1] * (double)ih1;
                a2 += (double)s_a[g][s+2] * (double)ih2;
                a3 += (double)s_a[g][s+3] * (double)ih3;
            }
            s_x[g][NH + j] = (float)(((a0 + a1) + (a2 + a3)));
            int sp = s_sol1[g][t];
            s_x[g][j] = fmaf(s_c0[g][sp], t_wr0[j], fmaf(s_c1[g][sp], t_wr1[j], t_br[j]));
        }
        __syncthreads();
        if (half == 0) {    // GRUd x-side (K=256), fused 3 rows
            float a00,a01,a10,a11,a20,a21;
            dot2x3f<64>(grud_Wih + (size_t)j * 256, grud_Wih + (size_t)(NH + j) * 256,
                        grud_Wih + (size_t)(2*NH + j) * 256, s_x[0], s_x[1],
                        a00,a01,a10,a11,a20,a21);
            s_pa[0][j] = a00;        s_pa[1][j] = a01;
            s_pa[0][NH + j] = a10;   s_pa[1][NH + j] = a11;
            s_pa[0][2*NH + j] = a20; s_pa[1][2*NH + j] = a21;
        } else {            // GRUd h-side, fused 3 rows
            float a00,a01,a10,a11,a20,a21;
            dot2x3f<32>(grud_Whh + (size_t)j * NH, grud_Whh + (size_t)(NH + j) * NH,
                        grud_Whh + (size_t)(2*NH + j) * NH, s_h2[0], s_h2[1],
                        a00,a01,a10,a11,a20,a21);
            s_pb[0][j] = a00;        s_pb[1][j] = a01;
            s_pb[0][NH + j] = a10;   s_pb[1][NH + j] = a11;
            s_pb[0][2*NH + j] = a20; s_pb[1][2*NH + j] = a21;
        }
        __syncthreads();
        gruc(t_dbih, t_dbhh, s_pa[g], s_pb[g], s_h2[g], j);
        __syncthreads();
    }

    // ---------- epilogue: mu, lv, Z (f64, R9 verbatim) ----------
    for (int idx = tid; idx < GPB * NS; idx += NTHR) {
        int gg = idx / NS, s = idx - gg * NS, b = bbase + gg;
        double mu = dotwd<32>(efc1_W + (size_t)s * NH, s_h2[gg]) + (double)efc1_b[s];
        double lv = dotwd<32>(efc2_W + (size_t)s * NH, s_h2[gg]) + (double)efc2_b[s];
        double z  = mu + (double)eps[(size_t)b * NS + s] * exp(0.5 * lv);
        out[OUT_MU + b * NS + s] = (float)mu;
        out[OUT_LV + b * NS + s] = (float)lv;
        out[OUT_Z  + b * NS + s] = (float)z;
        s_x[gg][NH + s] = (float)z;   // decoder Z slot [128..227]
    }
    for (int i = tid; i < GPB * NS; i += NTHR) {
        int gg = i / NS, s = i - gg * NS;
        s_msk[gg][s] = 1.f;
    }
    s_h1[g][j] = 0.f;
    __syncthreads();
    if (tid < GPB) {
        int b = bbase + tid;
        int s0 = s_sol2[tid][0];
        s_msk[tid][s0] = 0.f;
        s_rc0[tid] = s_c0[tid][s0];
        s_rc1[tid] = s_c1[tid][s0];
        out[OUT_TI + b * NS + 0] = (float)s0;
    }
    __syncthreads();

    // ---------- decoder ----------
    for (int t = 1; t < NS; ++t) {
        s_x[g][228 + j] = fmaf(s_rc0[g], t_wr0[j], fmaf(s_rc1[g], t_wr1[j], t_br[j]));
        __syncthreads();
        if (half == 0) {    // GRU1 x-side on ref
            float a00,a01,a10,a11,a20,a21;
            dot2x3f<32>(gru_Wih + (size_t)j * NH, gru_Wih + (size_t)(NH + j) * NH,
                        gru_Wih + (size_t)(2*NH + j) * NH, s_x[0]+228, s_x[1]+228,
                        a00,a01,a10,a11,a20,a21);
            s_pa[0][j] = a00;        s_pa[1][j] = a01;
            s_pa[0][NH + j] = a10;   s_pa[1][NH + j] = a11;
            s_pa[0][2*NH + j] = a20; s_pa[1][2*NH + j] = a21;
        } else {
            float a00,a01,a10,a11,a20,a21;
            dot2x3f<32>(gru_Whh + (size_t)j * NH, gru_Whh + (size_t)(NH + j) * NH,
                        gru_Whh + (size_t)(2*NH + j) * NH, s_h1[0], s_h1[1],
                        a00,a01,a10,a11,a20,a21);
            s_pb[0][j] = a00;        s_pb[1][j] = a01;
            s_pb[0][NH + j] = a10;   s_pb[1][NH + j] = a11;
            s_pb[0][2*NH + j] = a20; s_pb[1][2*NH + j] = a21;
        }
        __syncthreads();
        gruc(t_gbih, t_gbhh, s_pa[g], s_pb[g], s_h1[g], j);
        __syncthreads();
        {   // q k-split (attn)
            const float* col = attn_W + (size_t)NH * NH + j;
            const int k0 = half * 64;
            double a00=0.0,a01=0.0,a02=0.0,a03=0.0;
            double a10=0.0,a11=0.0,a12=0.0,a13=0.0;
            #pragma unroll 8
            for (int k = 0; k < 64; k += 4) {
                float w0 = col[(size_t)(k0+k+0) * NH];
                float w1 = col[(size_t)(k0+k+1) * NH];
                float w2 = col[(size_t)(k0+k+2) * NH];
                float w3 = col[(size_t)(k0+k+3) * NH];
                float4 h0 = *reinterpret_cast<const float4*>(&s_h1[0][k0+k]);
                float4 h1v = *reinterpret_cast<const float4*>(&s_h1[1][k0+k]);
                a00 = fma((double)w0, (double)h0.x, a00);
                a01 = fma((double)w1, (double)h0.y, a01);
                a02 = fma((double)w2, (double)h0.z, a02);
                a03 = fma((double)w3, (double)h0.w, a03);
                a10 = fma((double)w0, (double)h1v.x, a10);
                a11 = fma((double)w1, (double)h1v.y, a11);
                a12 = fma((double)w2, (double)h1v.z, a12);
                a13 = fma((double)w3, (double)h1v.w, a13);
            }
            if (half == 0) { s_qpA[0][j] = (a00+a01)+(a02+a03); s_qpA[1][j] = (a10+a11)+(a12+a13); }
            else           { s_qpB[0][j] = (a00+a01)+(a02+a03); s_qpB[1][j] = (a10+a11)+(a12+a13); }
        }
        __syncthreads();
        s_qh[g][j] = dAba[j] + (s_qpA[g][j] + s_qpB[g][j]);
        __syncthreads();
        if (j < NS) {   // relu head (f64, split chains)
            double c00 = (double)s_c0[g][j], c10 = (double)s_c1[g][j];
            double acc0 = 0.0, acc1 = 0.0, acc2 = 0.0, acc3 = 0.0;
            #pragma unroll 4
            for (int h = 0; h < NH; h += 4) {
                double2 A0 = dAa[h+0], A1 = dAa[h+1], A2 = dAa[h+2], A3 = dAa[h+3];
                double p0 = fma(c00, A0.x, fma(c10, A0.y, s_qh[g][h+0]));
                double p1 = fma(c00, A1.x, fma(c10, A1.y, s_qh[g][h+1]));
                double p2 = fma(c00, A2.x, fma(c10, A2.y, s_qh[g][h+2]));
                double p3 = fma(c00, A3.x, fma(c10, A3.y, s_qh[g][h+3]));
                acc0 = fma(fmax(p0, 0.0), (double)t_va[h+0], acc0);
                acc1 = fma(fmax(p1, 0.0), (double)t_va[h+1], acc1);
                acc2 = fma(fmax(p2, 0.0), (double)t_va[h+2], acc2);
                acc3 = fma(fmax(p3, 0.0), (double)t_va[h+3], acc3);
            }
            s_lg[g][j] = (float)(((acc0 + acc1) + (acc2 + acc3)));
        }
        __syncthreads();
        {   // fused: wave max + exp + wave f64 partial sum (softmax1)
            float a = s_lg[g][lane];
            float b = (lane + 64 < NS) ? s_lg[g][lane + 64] : NEGF;
            float m = fmaxf(a, b);
            m = fmaxf(m, __shfl_xor(m, 32)); m = fmaxf(m, __shfl_xor(m, 16));
            m = fmaxf(m, __shfl_xor(m, 8));  m = fmaxf(m, __shfl_xor(m, 4));
            m = fmaxf(m, __shfl_xor(m, 2));  m = fmaxf(m, __shfl_xor(m, 1));
            float fv = 0.f;
            if (j < NS) { fv = (float)exp((double)s_lg[g][j] - (double)m); s_a[g][j] = fv; }
            double ps = (double)fv;
            ps += __shfl_xor(ps, 32); ps += __shfl_xor(ps, 16);
            ps += __shfl_xor(ps, 8);  ps += __shfl_xor(ps, 4);
            ps += __shfl_xor(ps, 2);  ps += __shfl_xor(ps, 1);
            if (lane == 0) s_redd[g][wid] = ps;
        }
        __syncthreads();
        if (j < NS) {
            double se = s_redd[g][0] + s_redd[g][1];
            s_a[g][j] = (float)((double)s_a[g][j] / se);
        }
        __syncthreads();
        {   // context -> s_x[g][0..127] (f64, split chains)
            float w0 = t_wi0[j], w1 = t_wi1[j], bb = t_bi[j];
            double a0 = 0.0, a1 = 0.0, a2 = 0.0, a3 = 0.0;
            #pragma unroll 5
            for (int s = 0; s < NS; s += 4) {
                float ih0 = fmaf(s_c0[g][s+0], w0, fmaf(s_c1[g][s+0], w1, bb));
                float ih1 = fmaf(s_c0[g][s+1], w0, fmaf(s_c1[g][s+1], w1, bb));
                float ih2 = fmaf(s_c0[g][s+2], w0, fmaf(s_c1[g][s+2], w1, bb));
                float ih3 = fmaf(s_c0[g][s+3], w0, fmaf(s_c1[g][s+3], w1, bb));
                a0 += (double)s_a[g][s+0] * (double)ih0;
                a1 += (double)s_a[g][s+1] * (double)ih1;
                a2 += (double)s_a[g][s+2] * (double)ih2;
                a3 += (double)s_a[g][s+3] * (double)ih3;
            }
            s_x[g][j] = (float)(((a0 + a1) + (a2 + a3)));
        }
        __syncthreads();
        {   // pfc1: row i = tid, one read -> 2 batches (f32, R9 chain)
            float r0, r1;
            dot2f<89>(pfc1_W + (size_t)tid * 356, s_x[0], s_x[1], r0, r1);
            float bb = t_p1b[tid];
            s_fch[0][tid] = r0 + bb; s_fch[1][tid] = r1 + bb;
        }
        __syncthreads();
        {   // pfc2 (f32)
            float r0;
            dot1f<64>(pfc2_W + (size_t)j * 256, s_fch[g], r0);
            s_fco[g][j] = r0 + t_p2b[j];
        }
        __syncthreads();
        {   // q2 k-split (ptr)
            const float* col = ptr_W + (size_t)NH * NH + j;
            const int k0 = half * 64;
            double a00=0.0,a01=0.0,a02=0.0,a03=0.0;
            double a10=0.0,a11=0.0,a12=0.0,a13=0.0;
            #pragma unroll 8
            for (int k = 0; k < 64; k += 4) {
                float w0 = col[(size_t)(k0+k+0) * NH];
                float w1 = col[(size_t)(k0+k+1) * NH];
                float w2 = col[(size_t)(k0+k+2) * NH];
                float w3 = col[(size_t)(k0+k+3) * NH];
                float4 f0 = *reinterpret_cast<const float4*>(&s_fco[0][k0+k]);
                float4 f1 = *reinterpret_cast<const float4*>(&s_fco[1][k0+k]);
                a00 = fma((double)w0, (double)f0.x, a00);
                a01 = fma((double)w1, (double)f0.y, a01);
                a02 = fma((double)w2, (double)f0.z, a02);
                a03 = fma((double)w3, (double)f0.w, a03);
                a10 = fma((double)w0, (double)f1.x, a10);
                a11 = fma((double)w1, (double)f1.y, a11);
                a12 = fma((double)w2, (double)f1.z, a12);
                a13 = fma((double)w3, (double)f1.w, a13);
            }
            if (half == 0) { s_qpA[0][j] = (a00+a01)+(a02+a03); s_qpA[1][j] = (a10+a11)+(a12+a13); }
            else           { s_qpB[0][j] = (a00+a01)+(a02+a03); s_qpB[1][j] = (a10+a11)+(a12+a13); }
        }
        __syncthreads();
        s_qh[g][j] = dAbp[j] + (s_qpA[g][j] + s_qpB[g][j]);
        __syncthreads();
        if (j < NS) {   // tanh pointer head (f64 pre, tanhf, split chains)
            double c00 = (double)s_c0[g][j], c10 = (double)s_c1[g][j];
            double acc0 = 0.0, acc1 = 0.0, acc2 = 0.0, acc3 = 0.0;
            #pragma unroll 4
            for (int h = 0; h < NH; h += 4) {
                double2 A0 = dAp[h+0], A1 = dAp[h+1], A2 = dAp[h+2], A3 = dAp[h+3];
                double p0 = fma(c00, A0.x, fma(c10, A0.y, s_qh[g][h+0]));
                double p1 = fma(c00, A1.x, fma(c10, A1.y, s_qh[g][h+1]));
                double p2 = fma(c00, A2.x, fma(c10, A2.y, s_qh[g][h+2]));
                double p3 = fma(c00, A3.x, fma(c10, A3.y, s_qh[g][h+3]));
                acc0 = fma((double)tanhf((float)p0), (double)t_vp[h+0], acc0);
                acc1 = fma((double)tanhf((float)p1), (double)t_vp[h+1], acc1);
                acc2 = fma((double)tanhf((float)p2), (double)t_vp[h+2], acc2);
                acc3 = fma((double)tanhf((float)p3), (double)t_vp[h+3], acc3);
            }
            s_lg[g][j] = (float)(((acc0 + acc1) + (acc2 + acc3)));
        }
        __syncthreads();
        {   // fused masked max + exps + wave argmax + wave f64 sum (softmax2)
            float la = s_lg[g][lane];
            float ma = (s_msk[g][lane] > 0.f) ? la : NEGF;
            float lb = NEGF;
            if (lane + 64 < NS) lb = (s_msk[g][lane + 64] > 0.f) ? s_lg[g][lane + 64] : NEGF;
            float m = fmaxf(ma, lb);
            m = fmaxf(m, __shfl_xor(m, 32)); m = fmaxf(m, __shfl_xor(m, 16));
            m = fmaxf(m, __shfl_xor(m, 8));  m = fmaxf(m, __shfl_xor(m, 4));
            m = fmaxf(m, __shfl_xor(m, 2));  m = fmaxf(m, __shfl_xor(m, 1));
            float fv = 0.f;
            if (j < NS) {
                fv = (s_msk[g][j] > 0.f) ? (float)exp((double)s_lg[g][j] - (double)m) : 0.f;
                s_a[g][j] = fv;
            }
            float  bv = (j < NS) ? fv : -1.f;
            int    bi = (j < NS) ? j  : NS;
            double ps = (j < NS) ? (double)fv : 0.0;
            #pragma unroll
            for (int o = 32; o >= 1; o >>= 1) {
                float  ov = __shfl_xor(bv, o);
                int    oi = __shfl_xor(bi, o);
                double op = __shfl_xor(ps, o);
                ps += op;
                if (ov > bv || (ov == bv && oi < bi)) { bv = ov; bi = oi; }
            }
            if (lane == 0) { s_red[g][wid] = bv; s_ri[g][wid] = bi; s_redd[g][wid] = ps; }
        }
        __syncthreads();
        if (tid < GPB) {   // fold: 2 wave candidates; outputs + carry
            int gg = tid, b = bbase + gg;
            float m = -1.f; int mi = NS; double se = 0.0;
            for (int i = 0; i < 2; ++i) {
                se += s_redd[gg][i];
                float v = s_red[gg][i]; int vi = s_ri[gg][i];
                if (v > m || (v == m && vi < mi)) { m = v; mi = vi; }
            }
            int pt = s_sol2[gg][t];
            double logp = log((double)s_a[gg][pt] / se);
            out[OUT_TI + b * NS + t]             = (float)mi;
            out[OUT_LP + b * (NS - 1) + (t - 1)] = (float)logp;
            s_msk[gg][pt] = 0.f;
            s_rc0[gg] = s_c0[gg][pt];
            s_rc1[gg] = s_c1[gg][pt];
        }
        __syncthreads();
    }
}

extern "C" void kernel_launch(void* const* d_in, const int* in_sizes, int n_in,
                              void* d_out, int out_size, void* d_ws, size_t ws_size,
                              hipStream_t stream)
{
    (void)in_sizes; (void)n_in; (void)out_size; (void)d_ws; (void)ws_size;
    vae_v14<<<NBLK, NTHR, 0, stream>>>(
        (const float*)d_in[0], (const int*)d_in[1], (const int*)d_in[2], (const float*)d_in[3],
        (const float*)d_in[4], (const float*)d_in[5], (const float*)d_in[6], (const float*)d_in[7],
        (const float*)d_in[8], (const float*)d_in[9], (const float*)d_in[10], (const float*)d_in[11],
        (const float*)d_in[12], (const float*)d_in[13], (const float*)d_in[14], (const float*)d_in[15],
        (const float*)d_in[16], (const float*)d_in[17], (const float*)d_in[18], (const float*)d_in[19],
        (const float*)d_in[20], (const float*)d_in[21], (const float*)d_in[22], (const float*)d_in[23],
        (const float*)d_in[24], (const float*)d_in[25], (const float*)d_in[26], (const float*)d_in[27],
        (float*)d_out);
}